// Round 11
// baseline (584.305 us; speedup 1.0000x reference)
//
#include <hip/hip_runtime.h>

typedef unsigned short u16;
typedef __attribute__((ext_vector_type(8))) short short8;
typedef __attribute__((ext_vector_type(4))) float f32x4;
typedef __attribute__((ext_vector_type(2))) unsigned int u32x2;

#define NPTS 1048576
#define TILES 128
#define NBLK (NPTS / (32 * TILES))   // 256 blocks = 1 per CU
#define HPE 72    // 64-col row stride (144 B)
#define HPB 264   // 256-col row stride (528 B)
#define HPF 136   // 128-col row stride (272 B)

__device__ __forceinline__ u16 f2b(float f) {
    return (u16)((__float_as_uint(f) + 0x8000u) >> 16);
}
#define INV2PI 0.15915494309189535f
__device__ __forceinline__ float sinrev(float t) {
    t = t - floorf(t);
    return __builtin_amdgcn_sinf(t);
}

// Barrier with LDS-only drain (R10-verified +15us): __syncthreads() would drain
// vmcnt(0) (global loads + store acks) at every phase; only LDS visibility needed.
__device__ __forceinline__ void bar_lds() {
    asm volatile("s_waitcnt lgkmcnt(0)\n\ts_barrier" ::: "memory");
}

// ---------------- weight convert(fp32->bf16) + transpose/pad prepass ----------------
// ws layout (bf16), WT[n][k] row-major in k:
//  WT1  @      0 : 256 x  64   (W1 63x256; k==63 = b1[n] bias fold, act col63=1.0)
//  WT2  @  16384 : 256 x 256
//  WT3  @  81920 : 256 x 256
//  WT4  @ 147456 :  16 x 256
//  WTc1 @ 151552 : 128 x  64   (Wc1 42x128; k==42 = bc1[n]; k>42 -> 0)
//  WTc2 @ 159744 :  16 x 128   (Wc2 128x3, n>=3 -> 0)
__global__ void prep_weights(const float* __restrict__ W1, const float* __restrict__ b1,
                             const float* __restrict__ W2,
                             const float* __restrict__ W3, const float* __restrict__ W4,
                             const float* __restrict__ Wc1, const float* __restrict__ bc1,
                             const float* __restrict__ Wc2,
                             u16* __restrict__ ws) {
    int i = blockIdx.x * 256 + threadIdx.x;
    if (i < 16384) { int n = i >> 6, k = i & 63;  ws[i]          = (k < 63) ? f2b(W1[k * 256 + n]) : f2b(b1[n]); return; }
    i -= 16384;
    if (i < 65536) { int n = i >> 8, k = i & 255; ws[16384 + i]  = f2b(W2[k * 256 + n]); return; }
    i -= 65536;
    if (i < 65536) { int n = i >> 8, k = i & 255; ws[81920 + i]  = f2b(W3[k * 256 + n]); return; }
    i -= 65536;
    if (i < 4096)  { int n = i >> 8, k = i & 255; ws[147456 + i] = f2b(W4[k * 16 + n]); return; }
    i -= 4096;
    if (i < 8192)  { int n = i >> 6, k = i & 63;
                     ws[151552 + i] = (k < 42) ? f2b(Wc1[k * 128 + n]) : ((k == 42) ? f2b(bc1[n]) : (u16)0); return; }
    i -= 8192;
    if (i < 2048)  { int n = i >> 7, k = i & 127; ws[159744 + i] = (n < 3) ? f2b(Wc2[k * 3 + n]) : (u16)0; return; }
}

// 16x16x32 layer: A=weights (m=neuron), B=acts (n=batch row). Per wave: 32 neurons
// (nbase..nbase+31) x 32 rows via 4 INDEPENDENT 16x16 tiles (sub=neuron-half,
// rh=row-half) -> 4 indep accumulator chains of NK32 (vs 1x16 dependent with
// 32x32x16). Same registers (acc 4xf32x4=16), same LDS traffic (2 reads/kt).
// Fragment patterns identical to the (verified) L4/head paths:
//   A: lane m=lr, k=kt*32+q*8..+8 ; B: lane n=lr, same k ; D: col=lr (row), row=q*4+r (neuron).
// wr layout: wr[sub*NK32 + kt] = WT[(nbase+sub*16+lr)*KS + kt*32 + q*8].
template <int NK32, bool BIAS>
__device__ __forceinline__ void layer16(const short8* wr, const u16* src, int ss,
                                        u16* dst, int ds, const float* bias,
                                        int nbase, int lr, int q) {
    f32x4 a00 = {0.f,0.f,0.f,0.f}, a01 = {0.f,0.f,0.f,0.f};
    f32x4 a10 = {0.f,0.f,0.f,0.f}, a11 = {0.f,0.f,0.f,0.f};
#pragma unroll
    for (int kt = 0; kt < NK32; ++kt) {
        const short8 b0 = *(const short8*)(src + lr * ss + kt * 32 + q * 8);
        const short8 b1 = *(const short8*)(src + (16 + lr) * ss + kt * 32 + q * 8);
        a00 = __builtin_amdgcn_mfma_f32_16x16x32_bf16(wr[kt], b0, a00, 0, 0, 0);
        a01 = __builtin_amdgcn_mfma_f32_16x16x32_bf16(wr[kt], b1, a01, 0, 0, 0);
        a10 = __builtin_amdgcn_mfma_f32_16x16x32_bf16(wr[NK32 + kt], b0, a10, 0, 0, 0);
        a11 = __builtin_amdgcn_mfma_f32_16x16x32_bf16(wr[NK32 + kt], b1, a11, 0, 0, 0);
    }
#pragma unroll
    for (int sub = 0; sub < 2; ++sub) {
        const int mq = nbase + sub * 16 + q * 4;
        f32x4 bi;
        if (BIAS) bi = *(const f32x4*)(bias + mq);
#pragma unroll
        for (int rh = 0; rh < 2; ++rh) {
            const f32x4 a = sub ? (rh ? a11 : a10) : (rh ? a01 : a00);
            float v[4];
#pragma unroll
            for (int j = 0; j < 4; ++j) v[j] = BIAS ? (a[j] + bi[j]) : a[j];
#pragma unroll
            for (int j = 0; j < 4; ++j) v[j] = fmaxf(v[j], 0.f);
            unsigned int u[4];
#pragma unroll
            for (int j = 0; j < 4; ++j) u[j] = __float_as_uint(v[j]) + 0x8000u;
            u32x2 d;
            d.x = __builtin_amdgcn_perm(u[1], u[0], 0x07060302);
            d.y = __builtin_amdgcn_perm(u[3], u[2], 0x07060302);
            *(u32x2*)(dst + (rh * 16 + lr) * ds + mq) = d;
        }
    }
}

// ---- encode split into preload (global loads, issued early) + compute ----
// j in [0,512): j<256 -> pos-encode job, else dir-encode job.
__device__ __forceinline__ void enc_preload(const float* __restrict__ pos,
                                            const float* __restrict__ dir,
                                            long rb, int j, float* v) {
    if (j < 256) {
        const long row = rb + (j >> 3);
        v[0] = pos[row * 3 + 0]; v[1] = pos[row * 3 + 1]; v[2] = pos[row * 3 + 2];
    } else {
        const long row = rb + ((j - 256) >> 3);
        v[0] = dir[row * 3 + 0]; v[1] = dir[row * 3 + 1]; v[2] = dir[row * 3 + 2];
    }
}

__device__ __forceinline__ void enc_compute(const float* v, int j, u16* sEj, u16* sGj) {
    if (j < 256) {
        const int r = j >> 3, g = j & 7;
        float xn[3];
#pragma unroll
        for (int c = 0; c < 3; ++c) xn[c] = v[c] * (1.0f / 1.5f);
        u16* er = sEj + r * HPE;
        if (g < 5) {
#pragma unroll
            for (int dd = 0; dd < 2; ++dd) {
                const int d = 2 * g + dd;
                const float sc = (float)(1 << d);
#pragma unroll
                for (int c = 0; c < 3; ++c) {
                    float tv = xn[c] * sc * INV2PI;
                    er[3 + d * 3 + c]  = f2b(sinrev(tv));
                    er[33 + d * 3 + c] = f2b(sinrev(tv + 0.25f));
                }
            }
        } else if (g == 5) {
            er[0] = f2b(xn[0]); er[1] = f2b(xn[1]); er[2] = f2b(xn[2]);
            er[63] = 0x3F80;   // 1.0 -> b1 fold
        }
    } else {
        const int j2 = j - 256;
        const int r = j2 >> 3, g = j2 & 7;
        u16* gr = sGj + r * HPE;
        const float dx = v[0], dy = v[1], dz = v[2];
        if (g < 6) {
            const float nrm = sqrtf(dx * dx + dy * dy + dz * dz);
            const float inv = 1.f / fmaxf(nrm, 1e-12f);
            const float dn[3] = {dx * inv, dy * inv, dz * inv};
            if (g < 4) {
                const float sc = (float)(1 << g);
#pragma unroll
                for (int c = 0; c < 3; ++c) {
                    float tv = dn[c] * sc * INV2PI;
                    gr[18 + g * 3 + c] = f2b(sinrev(tv));
                    gr[30 + g * 3 + c] = f2b(sinrev(tv + 0.25f));
                }
            } else if (g == 4) {
                gr[15] = f2b(dn[0]); gr[16] = f2b(dn[1]); gr[17] = f2b(dn[2]);
            } else {
                gr[42] = 0x3F80;  // 1.0 -> bc1 fold
#pragma unroll
                for (int c = 43; c < 50; ++c) gr[c] = 0;
            }
        } else if (g == 6) {
#pragma unroll
            for (int c = 50; c < 57; ++c) gr[c] = 0;
        } else {
#pragma unroll
            for (int c = 57; c < 64; ++c) gr[c] = 0;
        }
    }
}

// Producer/consumer wave-specialized fused MLP: 16 waves (4/SIMD), 1 block/CU.
// R10 schedule (bar_lds barriers), layers via 16x16x32 (4 indep chains/wave):
//   A(i): front: enc_preload(i+1); L1(i): sE->sB; enc_compute(i+1)->sE',sG
//         back:  L3(i-1): sC->sD
//   B(i): front: L2(i): sB->sC
//         back:  bw4,5: L4(i-1): sD->sG.feat+density | bw0-3: ch1(i-2): sG->sF
//                | bw6,7: head(i-3): sF->rgb
// Buffers: sE x2 (enc j -> buf j&1), sG x4 (dir j @A(j-1) slot j&3, feat @B(j+1),
//          read @B(j+2), reuse @A(j+3)), sF x2 (ch1 j -> buf j&1, head reads @B(j+3)).
__global__ __launch_bounds__(1024, 4) void ngp_fused(
    const float* __restrict__ pos, const float* __restrict__ dir, const u16* __restrict__ ws,
    const float* __restrict__ b2, const float* __restrict__ b3,
    const float* __restrict__ b4, const float* __restrict__ bc2,
    float* __restrict__ out) {
    __shared__ __align__(16) u16 sE[2][32][HPE];    // encode out (64c), double-buffered
    __shared__ __align__(16) u16 sB[32][HPB];       // L1 out (256c)
    __shared__ __align__(16) u16 sC[32][HPB];       // L2 out (256c)
    __shared__ __align__(16) u16 sD[32][HPB];       // L3 out (256c)
    __shared__ __align__(16) u16 sG[4][32][HPE];    // color in (64c), 4-deep rotation
    __shared__ __align__(16) u16 sF[2][32][HPF];    // ch1 out (128c)
    const int t = threadIdx.x;
    const int lane = t & 63;
    const int w = t >> 6;                        // 16 waves
    const int bw = w - 8;                        // back-wave index (valid w>=8)
    const int lr = lane & 15, q = lane >> 4;     // 16x16 frag coords

    const u16* WT1  = ws;
    const u16* WT2  = ws + 16384;
    const u16* WT3  = ws + 81920;
    const u16* WT4  = ws + 147456;
    const u16* WTc1 = ws + 151552;
    const u16* WTc2 = ws + 159744;

    // ---- resident weights (16x16x32 A-fragments), unioned across roles ----
    // wrA[sub*8+kt] = WTbig[(nb+sub*16+lr)*256 + kt*32 + q*8]   (W2 front / W3 back)
    // wrB[sub*2+kt] = WTsm [(nb+sub*16+lr)*64  + kt*32 + q*8]   (W1 front / Wc1 bw<4)
    short8 wrA[16], wrB[4];
    {
        const u16* baseA = (w < 8) ? WT2 : WT3;
        const int  nbA   = (w < 8) ? w * 32 : bw * 32;
#pragma unroll
        for (int sub = 0; sub < 2; ++sub)
#pragma unroll
        for (int kt = 0; kt < 8; ++kt)
            wrA[sub * 8 + kt] =
                *(const short8*)(baseA + (size_t)(nbA + sub * 16 + lr) * 256 + kt * 32 + q * 8);
        const u16* baseB = (w < 8) ? WT1 : WTc1;
        const int  nbB   = (w < 8) ? w * 32 : ((bw < 4) ? bw * 32 : 0);   // bw>=4: dummy
#pragma unroll
        for (int sub = 0; sub < 2; ++sub)
#pragma unroll
        for (int kt = 0; kt < 2; ++kt)
            wrB[sub * 2 + kt] =
                *(const short8*)(baseB + (size_t)(nbB + sub * 16 + lr) * 64 + kt * 32 + q * 8);
    }

    // ---- prologue: encode tile 0 ----
    {
        float pv[3];
        if (t < 512) {
            enc_preload(pos, dir, (long)blockIdx.x * TILES * 32, t, pv);
            enc_compute(pv, t, &sE[0][0][0], &sG[0][0][0]);
        }
        bar_lds();
    }

    for (int i = 0; i <= TILES + 2; ++i) {
        const bool dEnc = (i + 1 < TILES);
        const bool dL1  = (i < TILES);
        const bool dL3  = (i >= 1 && i <= TILES);
        const bool dC1  = (i >= 2 && i <= TILES + 1);
        const bool dHd  = (i >= 3);

        // ========== Phase A: enc_preload(i+1)+L1(i)+enc_compute(i+1) [front] | L3(i-1) [back] ==========
        float pv[3];
        if (dEnc && t < 512)
            enc_preload(pos, dir, ((long)blockIdx.x * TILES + i + 1) * 32, t, pv);
        if (dL1 && w < 8)
            layer16<2, false>(wrB, &sE[i & 1][0][0], HPE, &sB[0][0], HPB, nullptr, w * 32, lr, q);
        if (dL3 && w >= 8)
            layer16<8, true>(wrA, &sC[0][0], HPB, &sD[0][0], HPB, b3, bw * 32, lr, q);
        if (dEnc && t < 512)
            enc_compute(pv, t, &sE[(i + 1) & 1][0][0], &sG[(i + 1) & 3][0][0]);
        bar_lds();

        // ========== Phase B: L2(i) [front] | L4(i-1) | ch1(i-2) | head(i-3) [back] ==========
        if (dL1 && w < 8)
            layer16<8, true>(wrA, &sB[0][0], HPB, &sC[0][0], HPB, b2, w * 32, lr, q);
        if (dL3 && w >= 8 && (bw == 4 || bw == 5)) {
            // L4(i-1): sD -> feat into sG[(i-1)&3] cols 0..14, density -> out
            const long rbM = ((long)blockIdx.x * TILES + i - 1) * 32;
            u16* sGf = &sG[(i - 1) & 3][0][0];
            const int rbase = (bw - 4) * 16;
            f32x4 acc = {0.f, 0.f, 0.f, 0.f};
#pragma unroll
            for (int kt = 0; kt < 8; ++kt) {
                const short8 aF = *(const short8*)&sD[rbase + lr][kt * 32 + q * 8];
                const short8 bF = *(const short8*)(WT4 + lr * 256 + kt * 32 + q * 8);
                acc = __builtin_amdgcn_mfma_f32_16x16x32_bf16(aF, bF, acc, 0, 0, 0);
            }
            const float bi = b4[lr];
#pragma unroll
            for (int r = 0; r < 4; ++r) {
                const float v = acc[r] + bi;
                const int gm = rbase + q * 4 + r;
                if (lr == 0)
                    out[3 * (long)NPTS + rbM + gm] = __expf(v - 1.f);
                else
                    sGf[gm * HPE + lr - 1] = f2b(v);   // feat -> cols 0..14
            }
        }
        if (dC1 && w >= 8 && bw < 4)
            layer16<2, false>(wrB, &sG[(i - 2) & 3][0][0], HPE, &sF[(i - 2) & 1][0][0], HPF,
                              nullptr, bw * 32, lr, q);
        if (dHd && w >= 8 && (bw == 6 || bw == 7)) {
            // head(i-3): sF[(i-3)&1] -> rgb out
            const long rbH = ((long)blockIdx.x * TILES + i - 3) * 32;
            const int rbase = (bw - 6) * 16;
            f32x4 acc = {0.f, 0.f, 0.f, 0.f};
#pragma unroll
            for (int kt = 0; kt < 4; ++kt) {
                const short8 aF = *(const short8*)&sF[(i - 3) & 1][rbase + lr][kt * 32 + q * 8];
                const short8 bF = *(const short8*)(WTc2 + lr * 128 + kt * 32 + q * 8);
                acc = __builtin_amdgcn_mfma_f32_16x16x32_bf16(aF, bF, acc, 0, 0, 0);
            }
            if (lr < 3) {
                const float bi = bc2[lr];
#pragma unroll
                for (int r = 0; r < 4; ++r) {
                    const float v = acc[r] + bi;
                    const float sg = 1.f / (1.f + __expf(-v));
                    out[(rbH + rbase + q * 4 + r) * 3 + lr] = sg;
                }
            }
        }
        bar_lds();
    }
}

extern "C" void kernel_launch(void* const* d_in, const int* in_sizes, int n_in,
                              void* d_out, int out_size, void* d_ws, size_t ws_size,
                              hipStream_t stream) {
    const float* pos = (const float*)d_in[0];
    const float* dir = (const float*)d_in[1];
    const float* W1  = (const float*)d_in[2];
    const float* b1  = (const float*)d_in[3];
    const float* W2  = (const float*)d_in[4];
    const float* b2  = (const float*)d_in[5];
    const float* W3  = (const float*)d_in[6];
    const float* b3  = (const float*)d_in[7];
    const float* W4  = (const float*)d_in[8];
    const float* b4  = (const float*)d_in[9];
    const float* Wc1 = (const float*)d_in[10];
    const float* bc1 = (const float*)d_in[11];
    const float* Wc2 = (const float*)d_in[12];
    const float* bc2 = (const float*)d_in[13];
    u16* ws   = (u16*)d_ws;
    float* out = (float*)d_out;

    prep_weights<<<633, 256, 0, stream>>>(W1, b1, W2, W3, W4, Wc1, bc1, Wc2, ws);
    ngp_fused<<<NBLK, 1024, 0, stream>>>(pos, dir, ws, b2, b3, b4, bc2, out);
}

// Round 12
// 552.668 us; speedup vs baseline: 1.0572x; 1.0572x over previous
//
#include <hip/hip_runtime.h>

typedef unsigned short u16;
typedef __attribute__((ext_vector_type(8))) short short8;
typedef __attribute__((ext_vector_type(4))) float f32x4;
typedef __attribute__((ext_vector_type(16))) float f32x16;
typedef __attribute__((ext_vector_type(2))) unsigned int u32x2;

#define NPTS 1048576
#define TILES 128
#define NBLK (NPTS / (32 * TILES))   // 256 blocks = 1 per CU
#define HPE 72    // 64-col row stride (144 B)
#define HPB 264   // 256-col row stride (528 B)
#define HPF 136   // 128-col row stride (272 B)

__device__ __forceinline__ u16 f2b(float f) {
    return (u16)((__float_as_uint(f) + 0x8000u) >> 16);
}
#define INV2PI 0.15915494309189535f
__device__ __forceinline__ float sinrev(float t) {
    t = t - floorf(t);
    return __builtin_amdgcn_sinf(t);
}

// Barrier with LDS-only drain (R10-verified +15us): __syncthreads() would drain
// vmcnt(0) (global loads + store acks) at every phase; only LDS visibility needed.
__device__ __forceinline__ void bar_lds() {
    asm volatile("s_waitcnt lgkmcnt(0)\n\ts_barrier" ::: "memory");
}

// ---------------- weight convert(fp32->bf16) + transpose/pad prepass ----------------
// ws layout (bf16), WT[n][k] row-major in k:
//  WT1  @      0 : 256 x  64   (W1 63x256; k==63 = b1[n] bias fold, act col63=1.0)
//  WT2  @  16384 : 256 x 256
//  WT3  @  81920 : 256 x 256
//  WT4  @ 147456 :  16 x 256
//  WTc1 @ 151552 : 128 x  64   (Wc1 42x128; k==42 = bc1[n]; k>42 -> 0)
//  WTc2 @ 159744 :  16 x 128   (Wc2 128x3, n>=3 -> 0)
__global__ void prep_weights(const float* __restrict__ W1, const float* __restrict__ b1,
                             const float* __restrict__ W2,
                             const float* __restrict__ W3, const float* __restrict__ W4,
                             const float* __restrict__ Wc1, const float* __restrict__ bc1,
                             const float* __restrict__ Wc2,
                             u16* __restrict__ ws) {
    int i = blockIdx.x * 256 + threadIdx.x;
    if (i < 16384) { int n = i >> 6, k = i & 63;  ws[i]          = (k < 63) ? f2b(W1[k * 256 + n]) : f2b(b1[n]); return; }
    i -= 16384;
    if (i < 65536) { int n = i >> 8, k = i & 255; ws[16384 + i]  = f2b(W2[k * 256 + n]); return; }
    i -= 65536;
    if (i < 65536) { int n = i >> 8, k = i & 255; ws[81920 + i]  = f2b(W3[k * 256 + n]); return; }
    i -= 65536;
    if (i < 4096)  { int n = i >> 8, k = i & 255; ws[147456 + i] = f2b(W4[k * 16 + n]); return; }
    i -= 4096;
    if (i < 8192)  { int n = i >> 6, k = i & 63;
                     ws[151552 + i] = (k < 42) ? f2b(Wc1[k * 128 + n]) : ((k == 42) ? f2b(bc1[n]) : (u16)0); return; }
    i -= 8192;
    if (i < 2048)  { int n = i >> 7, k = i & 127; ws[159744 + i] = (n < 3) ? f2b(Wc2[k * 3 + n]) : (u16)0; return; }
}

// Epilogue for 32x32x16 (A=weights, B=acts): lane = batch row, regs = 16 neurons.
template <bool BIAS>
__device__ __forceinline__ void epi32(const f32x16& acc, u16* rowp, const float* bias,
                                      int nbase, int kh) {
#pragma unroll
    for (int g = 0; g < 4; ++g) {
        const int mq = nbase + 8 * g + 4 * kh;
        float v[4];
#pragma unroll
        for (int j = 0; j < 4; ++j) v[j] = acc[4 * g + j];
        if (BIAS) {
            const f32x4 bi = *(const f32x4*)(bias + mq);
#pragma unroll
            for (int j = 0; j < 4; ++j) v[j] += bi[j];
        }
#pragma unroll
        for (int j = 0; j < 4; ++j) v[j] = fmaxf(v[j], 0.f);
        unsigned int u[4];
#pragma unroll
        for (int j = 0; j < 4; ++j) u[j] = __float_as_uint(v[j]) + 0x8000u;
        u32x2 d;
        d.x = __builtin_amdgcn_perm(u[1], u[0], 0x07060302);
        d.y = __builtin_amdgcn_perm(u[3], u[2], 0x07060302);
        *(u32x2*)(rowp + mq) = d;
    }
}

template <int NKT, bool BIAS>
__device__ __forceinline__ void layer32(const short8* wr, const u16* src, int ss,
                                        u16* dst, int ds, const float* bias,
                                        int nbase, int ln, int kh) {
    f32x16 acc;
#pragma unroll
    for (int r = 0; r < 16; ++r) acc[r] = 0.f;
    __builtin_amdgcn_s_setprio(1);
#pragma unroll
    for (int kt = 0; kt < NKT; ++kt) {
        const short8 bA = *(const short8*)(src + ln * ss + kt * 16 + kh * 8);
        acc = __builtin_amdgcn_mfma_f32_32x32x16_bf16(wr[kt], bA, acc, 0, 0, 0);
    }
    __builtin_amdgcn_s_setprio(0);
    epi32<BIAS>(acc, dst + ln * ds, bias, nbase, kh);
}

// ---- encode split into preload (global loads, issued early) + compute ----
// j in [0,512): j<256 -> pos-encode job, else dir-encode job.
__device__ __forceinline__ void enc_preload(const float* __restrict__ pos,
                                            const float* __restrict__ dir,
                                            long rb, int j, float* v) {
    if (j < 256) {
        const long row = rb + (j >> 3);
        v[0] = pos[row * 3 + 0]; v[1] = pos[row * 3 + 1]; v[2] = pos[row * 3 + 2];
    } else {
        const long row = rb + ((j - 256) >> 3);
        v[0] = dir[row * 3 + 0]; v[1] = dir[row * 3 + 1]; v[2] = dir[row * 3 + 2];
    }
}

__device__ __forceinline__ void enc_compute(const float* v, int j, u16* sEj, u16* sGj) {
    if (j < 256) {
        const int r = j >> 3, g = j & 7;
        float xn[3];
#pragma unroll
        for (int c = 0; c < 3; ++c) xn[c] = v[c] * (1.0f / 1.5f);
        u16* er = sEj + r * HPE;
        if (g < 5) {
#pragma unroll
            for (int dd = 0; dd < 2; ++dd) {
                const int d = 2 * g + dd;
                const float sc = (float)(1 << d);
#pragma unroll
                for (int c = 0; c < 3; ++c) {
                    float tv = xn[c] * sc * INV2PI;
                    er[3 + d * 3 + c]  = f2b(sinrev(tv));
                    er[33 + d * 3 + c] = f2b(sinrev(tv + 0.25f));
                }
            }
        } else if (g == 5) {
            er[0] = f2b(xn[0]); er[1] = f2b(xn[1]); er[2] = f2b(xn[2]);
            er[63] = 0x3F80;   // 1.0 -> b1 fold
        }
    } else {
        const int j2 = j - 256;
        const int r = j2 >> 3, g = j2 & 7;
        u16* gr = sGj + r * HPE;
        const float dx = v[0], dy = v[1], dz = v[2];
        if (g < 6) {
            const float nrm = sqrtf(dx * dx + dy * dy + dz * dz);
            const float inv = 1.f / fmaxf(nrm, 1e-12f);
            const float dn[3] = {dx * inv, dy * inv, dz * inv};
            if (g < 4) {
                const float sc = (float)(1 << g);
#pragma unroll
                for (int c = 0; c < 3; ++c) {
                    float tv = dn[c] * sc * INV2PI;
                    gr[18 + g * 3 + c] = f2b(sinrev(tv));
                    gr[30 + g * 3 + c] = f2b(sinrev(tv + 0.25f));
                }
            } else if (g == 4) {
                gr[15] = f2b(dn[0]); gr[16] = f2b(dn[1]); gr[17] = f2b(dn[2]);
            } else {
                gr[42] = 0x3F80;  // 1.0 -> bc1 fold
#pragma unroll
                for (int c = 43; c < 50; ++c) gr[c] = 0;
            }
        } else if (g == 6) {
#pragma unroll
            for (int c = 50; c < 57; ++c) gr[c] = 0;
        } else {
#pragma unroll
            for (int c = 57; c < 64; ++c) gr[c] = 0;
        }
    }
}

// Producer/consumer wave-specialized fused MLP: 16 waves (4/SIMD), 1 block/CU.
// R10 schedule (bar_lds barriers) + T5 setprio around MFMA clusters:
//   A(i): front: enc_preload(i+1); L1(i): sE->sB; enc_compute(i+1)->sE',sG
//         back:  L3(i-1): sC->sD
//   B(i): front: L2(i): sB->sC
//         back:  bw4,5: L4(i-1): sD->sG.feat+density | bw0-3: ch1(i-2): sG->sF
//                | bw6,7: head(i-3): sF->rgb
// Buffers: sE x2 (enc j -> buf j&1), sG x4 (dir j @A(j-1) slot j&3, feat @B(j+1),
//          read @B(j+2), reuse @A(j+3)), sF x2 (ch1 j -> buf j&1, head reads @B(j+3)).
__global__ __launch_bounds__(1024, 4) void ngp_fused(
    const float* __restrict__ pos, const float* __restrict__ dir, const u16* __restrict__ ws,
    const float* __restrict__ b2, const float* __restrict__ b3,
    const float* __restrict__ b4, const float* __restrict__ bc2,
    float* __restrict__ out) {
    __shared__ __align__(16) u16 sE[2][32][HPE];    // encode out (64c), double-buffered
    __shared__ __align__(16) u16 sB[32][HPB];       // L1 out (256c)
    __shared__ __align__(16) u16 sC[32][HPB];       // L2 out (256c)
    __shared__ __align__(16) u16 sD[32][HPB];       // L3 out (256c)
    __shared__ __align__(16) u16 sG[4][32][HPE];    // color in (64c), 4-deep rotation
    __shared__ __align__(16) u16 sF[2][32][HPF];    // ch1 out (128c)
    const int t = threadIdx.x;
    const int lane = t & 63;
    const int w = t >> 6;                        // 16 waves
    const int bw = w - 8;                        // back-wave index (valid w>=8)
    const int ln = lane & 31, kh = lane >> 5;    // 32x32 frag coords
    const int lr = lane & 15, q = lane >> 4;     // 16x16 frag coords

    const u16* WT1  = ws;
    const u16* WT2  = ws + 16384;
    const u16* WT3  = ws + 81920;
    const u16* WT4  = ws + 147456;
    const u16* WTc1 = ws + 151552;
    const u16* WTc2 = ws + 159744;

    // ---- resident weights, unioned across roles (shared physical regs) ----
    short8 wrA[16], wrB[4];
    {
        const u16* pA = (w < 8) ? WT2 + (size_t)(w * 32 + ln) * 256 + kh * 8
                                : WT3 + (size_t)(bw * 32 + ln) * 256 + kh * 8;
#pragma unroll
        for (int kt = 0; kt < 16; ++kt) wrA[kt] = *(const short8*)(pA + kt * 16);
        const u16* pB = (w < 8)  ? WT1 + (size_t)(w * 32 + ln) * 64 + kh * 8
                      : (bw < 4) ? WTc1 + (size_t)(bw * 32 + ln) * 64 + kh * 8
                                 : WT1 + (size_t)ln * 64 + kh * 8;   // dummy (unused)
#pragma unroll
        for (int kt = 0; kt < 4; ++kt) wrB[kt] = *(const short8*)(pB + kt * 16);
    }

    // ---- prologue: encode tile 0 ----
    {
        float pv[3];
        if (t < 512) {
            enc_preload(pos, dir, (long)blockIdx.x * TILES * 32, t, pv);
            enc_compute(pv, t, &sE[0][0][0], &sG[0][0][0]);
        }
        bar_lds();
    }

    for (int i = 0; i <= TILES + 2; ++i) {
        const bool dEnc = (i + 1 < TILES);
        const bool dL1  = (i < TILES);
        const bool dL3  = (i >= 1 && i <= TILES);
        const bool dC1  = (i >= 2 && i <= TILES + 1);
        const bool dHd  = (i >= 3);

        // ========== Phase A: enc_preload(i+1)+L1(i)+enc_compute(i+1) [front] | L3(i-1) [back] ==========
        float pv[3];
        if (dEnc && t < 512)
            enc_preload(pos, dir, ((long)blockIdx.x * TILES + i + 1) * 32, t, pv);
        if (dL1 && w < 8)
            layer32<4, false>(wrB, &sE[i & 1][0][0], HPE, &sB[0][0], HPB, nullptr, w * 32, ln, kh);
        if (dL3 && w >= 8)
            layer32<16, true>(wrA, &sC[0][0], HPB, &sD[0][0], HPB, b3, bw * 32, ln, kh);
        if (dEnc && t < 512)
            enc_compute(pv, t, &sE[(i + 1) & 1][0][0], &sG[(i + 1) & 3][0][0]);
        bar_lds();

        // ========== Phase B: L2(i) [front] | L4(i-1) | ch1(i-2) | head(i-3) [back] ==========
        if (dL1 && w < 8)
            layer32<16, true>(wrA, &sB[0][0], HPB, &sC[0][0], HPB, b2, w * 32, ln, kh);
        if (dL3 && w >= 8 && (bw == 4 || bw == 5)) {
            // L4(i-1): sD -> feat into sG[(i-1)&3] cols 0..14, density -> out
            const long rbM = ((long)blockIdx.x * TILES + i - 1) * 32;
            u16* sGf = &sG[(i - 1) & 3][0][0];
            const int rbase = (bw - 4) * 16;
            f32x4 acc = {0.f, 0.f, 0.f, 0.f};
            __builtin_amdgcn_s_setprio(1);
#pragma unroll
            for (int kt = 0; kt < 8; ++kt) {
                const short8 aF = *(const short8*)&sD[rbase + lr][kt * 32 + q * 8];
                const short8 bF = *(const short8*)(WT4 + lr * 256 + kt * 32 + q * 8);
                acc = __builtin_amdgcn_mfma_f32_16x16x32_bf16(aF, bF, acc, 0, 0, 0);
            }
            __builtin_amdgcn_s_setprio(0);
            const float bi = b4[lr];
#pragma unroll
            for (int r = 0; r < 4; ++r) {
                const float v = acc[r] + bi;
                const int gm = rbase + q * 4 + r;
                if (lr == 0)
                    out[3 * (long)NPTS + rbM + gm] = __expf(v - 1.f);
                else
                    sGf[gm * HPE + lr - 1] = f2b(v);   // feat -> cols 0..14
            }
        }
        if (dC1 && w >= 8 && bw < 4)
            layer32<4, false>(wrB, &sG[(i - 2) & 3][0][0], HPE, &sF[(i - 2) & 1][0][0], HPF,
                              nullptr, bw * 32, ln, kh);
        if (dHd && w >= 8 && (bw == 6 || bw == 7)) {
            // head(i-3): sF[(i-3)&1] -> rgb out
            const long rbH = ((long)blockIdx.x * TILES + i - 3) * 32;
            const int rbase = (bw - 6) * 16;
            f32x4 acc = {0.f, 0.f, 0.f, 0.f};
            __builtin_amdgcn_s_setprio(1);
#pragma unroll
            for (int kt = 0; kt < 4; ++kt) {
                const short8 aF = *(const short8*)&sF[(i - 3) & 1][rbase + lr][kt * 32 + q * 8];
                const short8 bF = *(const short8*)(WTc2 + lr * 128 + kt * 32 + q * 8);
                acc = __builtin_amdgcn_mfma_f32_16x16x32_bf16(aF, bF, acc, 0, 0, 0);
            }
            __builtin_amdgcn_s_setprio(0);
            if (lr < 3) {
                const float bi = bc2[lr];
#pragma unroll
                for (int r = 0; r < 4; ++r) {
                    const float v = acc[r] + bi;
                    const float sg = 1.f / (1.f + __expf(-v));
                    out[(rbH + rbase + q * 4 + r) * 3 + lr] = sg;
                }
            }
        }
        bar_lds();
    }
}

extern "C" void kernel_launch(void* const* d_in, const int* in_sizes, int n_in,
                              void* d_out, int out_size, void* d_ws, size_t ws_size,
                              hipStream_t stream) {
    const float* pos = (const float*)d_in[0];
    const float* dir = (const float*)d_in[1];
    const float* W1  = (const float*)d_in[2];
    const float* b1  = (const float*)d_in[3];
    const float* W2  = (const float*)d_in[4];
    const float* b2  = (const float*)d_in[5];
    const float* W3  = (const float*)d_in[6];
    const float* b3  = (const float*)d_in[7];
    const float* W4  = (const float*)d_in[8];
    const float* b4  = (const float*)d_in[9];
    const float* Wc1 = (const float*)d_in[10];
    const float* bc1 = (const float*)d_in[11];
    const float* Wc2 = (const float*)d_in[12];
    const float* bc2 = (const float*)d_in[13];
    u16* ws   = (u16*)d_ws;
    float* out = (float*)d_out;

    prep_weights<<<633, 256, 0, stream>>>(W1, b1, W2, W3, W4, Wc1, bc1, Wc2, ws);
    ngp_fused<<<NBLK, 1024, 0, stream>>>(pos, dir, ws, b2, b3, b4, bc2, out);
}

// Round 13
// 531.604 us; speedup vs baseline: 1.0991x; 1.0396x over previous
//
#include <hip/hip_runtime.h>

typedef unsigned short u16;
typedef __attribute__((ext_vector_type(8))) short short8;
typedef __attribute__((ext_vector_type(4))) float f32x4;
typedef __attribute__((ext_vector_type(16))) float f32x16;
typedef __attribute__((ext_vector_type(2))) unsigned int u32x2;

#define NPTS 1048576
#define TILES 128
#define NBLK (NPTS / (32 * TILES))   // 256 blocks = 1 per CU
#define HPE 72    // 64-col row stride (144 B)
#define HPB 264   // 256-col row stride (528 B)
#define HPF 136   // 128-col row stride (272 B)

__device__ __forceinline__ u16 f2b(float f) {
    return (u16)((__float_as_uint(f) + 0x8000u) >> 16);
}
#define INV2PI 0.15915494309189535f
__device__ __forceinline__ float sinrev(float t) {
    t = t - floorf(t);
    return __builtin_amdgcn_sinf(t);
}

// Barrier with LDS-only drain (R10-verified +15us): __syncthreads() would drain
// vmcnt(0) (global loads + store acks) at every phase; only LDS visibility needed.
__device__ __forceinline__ void bar_lds() {
    asm volatile("s_waitcnt lgkmcnt(0)\n\ts_barrier" ::: "memory");
}

// ---------------- weight convert(fp32->bf16) + transpose/pad prepass ----------------
// ws layout (bf16), WT[n][k] row-major in k:
//  WT1  @      0 : 256 x  64   (W1 63x256; k==63 = b1[n] bias fold, act col63=1.0)
//  WT2  @  16384 : 256 x 256
//  WT3  @  81920 : 256 x 256
//  WT4  @ 147456 :  16 x 256
//  WTc1 @ 151552 : 128 x  64   (Wc1 42x128; k==42 = bc1[n]; k>42 -> 0)
//  WTc2 @ 159744 :  16 x 128   (Wc2 128x3, n>=3 -> 0)
__global__ void prep_weights(const float* __restrict__ W1, const float* __restrict__ b1,
                             const float* __restrict__ W2,
                             const float* __restrict__ W3, const float* __restrict__ W4,
                             const float* __restrict__ Wc1, const float* __restrict__ bc1,
                             const float* __restrict__ Wc2,
                             u16* __restrict__ ws) {
    int i = blockIdx.x * 256 + threadIdx.x;
    if (i < 16384) { int n = i >> 6, k = i & 63;  ws[i]          = (k < 63) ? f2b(W1[k * 256 + n]) : f2b(b1[n]); return; }
    i -= 16384;
    if (i < 65536) { int n = i >> 8, k = i & 255; ws[16384 + i]  = f2b(W2[k * 256 + n]); return; }
    i -= 65536;
    if (i < 65536) { int n = i >> 8, k = i & 255; ws[81920 + i]  = f2b(W3[k * 256 + n]); return; }
    i -= 65536;
    if (i < 4096)  { int n = i >> 8, k = i & 255; ws[147456 + i] = f2b(W4[k * 16 + n]); return; }
    i -= 4096;
    if (i < 8192)  { int n = i >> 6, k = i & 63;
                     ws[151552 + i] = (k < 42) ? f2b(Wc1[k * 128 + n]) : ((k == 42) ? f2b(bc1[n]) : (u16)0); return; }
    i -= 8192;
    if (i < 2048)  { int n = i >> 7, k = i & 127; ws[159744 + i] = (n < 3) ? f2b(Wc2[k * 3 + n]) : (u16)0; return; }
}

// Epilogue for 32x32x16 (A=weights, B=acts): lane = batch row, regs = 16 neurons.
template <bool BIAS>
__device__ __forceinline__ void epi32(const f32x16& acc, u16* rowp, const float* bias,
                                      int nbase, int kh) {
#pragma unroll
    for (int g = 0; g < 4; ++g) {
        const int mq = nbase + 8 * g + 4 * kh;
        float v[4];
#pragma unroll
        for (int j = 0; j < 4; ++j) v[j] = acc[4 * g + j];
        if (BIAS) {
            const f32x4 bi = *(const f32x4*)(bias + mq);
#pragma unroll
            for (int j = 0; j < 4; ++j) v[j] += bi[j];
        }
#pragma unroll
        for (int j = 0; j < 4; ++j) v[j] = fmaxf(v[j], 0.f);
        unsigned int u[4];
#pragma unroll
        for (int j = 0; j < 4; ++j) u[j] = __float_as_uint(v[j]) + 0x8000u;
        u32x2 d;
        d.x = __builtin_amdgcn_perm(u[1], u[0], 0x07060302);
        d.y = __builtin_amdgcn_perm(u[3], u[2], 0x07060302);
        *(u32x2*)(rowp + mq) = d;
    }
}

template <int NKT, bool BIAS>
__device__ __forceinline__ void layer32(const short8* wr, const u16* src, int ss,
                                        u16* dst, int ds, const float* bias,
                                        int nbase, int ln, int kh) {
    f32x16 acc;
#pragma unroll
    for (int r = 0; r < 16; ++r) acc[r] = 0.f;
#pragma unroll
    for (int kt = 0; kt < NKT; ++kt) {
        const short8 bA = *(const short8*)(src + ln * ss + kt * 16 + kh * 8);
        acc = __builtin_amdgcn_mfma_f32_32x32x16_bf16(wr[kt], bA, acc, 0, 0, 0);
    }
    epi32<BIAS>(acc, dst + ln * ds, bias, nbase, kh);
}

// ---- encode split into preload (global loads, issued early) + compute ----
// j in [0,512): j<256 -> pos-encode job, else dir-encode job.
// Constant columns (sE col63, sG cols 42..63) are init'ed ONCE in the prologue
// and never rewritten: enc bodies for them are deleted (saves ~22 scattered
// ds_write_b16 + 3 divergent branch bodies per iteration on the front path).
__device__ __forceinline__ void enc_preload(const float* __restrict__ pos,
                                            const float* __restrict__ dir,
                                            long rb, int j, float* v) {
    if (j < 256) {
        const long row = rb + (j >> 3);
        v[0] = pos[row * 3 + 0]; v[1] = pos[row * 3 + 1]; v[2] = pos[row * 3 + 2];
    } else {
        const long row = rb + ((j - 256) >> 3);
        v[0] = dir[row * 3 + 0]; v[1] = dir[row * 3 + 1]; v[2] = dir[row * 3 + 2];
    }
}

__device__ __forceinline__ void enc_compute(const float* v, int j, u16* sEj, u16* sGj) {
    if (j < 256) {
        const int r = j >> 3, g = j & 7;
        float xn[3];
#pragma unroll
        for (int c = 0; c < 3; ++c) xn[c] = v[c] * (1.0f / 1.5f);
        u16* er = sEj + r * HPE;
        if (g < 5) {
#pragma unroll
            for (int dd = 0; dd < 2; ++dd) {
                const int d = 2 * g + dd;
                const float sc = (float)(1 << d);
#pragma unroll
                for (int c = 0; c < 3; ++c) {
                    float tv = xn[c] * sc * INV2PI;
                    er[3 + d * 3 + c]  = f2b(sinrev(tv));
                    er[33 + d * 3 + c] = f2b(sinrev(tv + 0.25f));
                }
            }
        } else if (g == 5) {
            er[0] = f2b(xn[0]); er[1] = f2b(xn[1]); er[2] = f2b(xn[2]);
            // er[63] = 1.0 is constant: prologue-initialized
        }
    } else {
        const int j2 = j - 256;
        const int r = j2 >> 3, g = j2 & 7;
        u16* gr = sGj + r * HPE;
        const float dx = v[0], dy = v[1], dz = v[2];
        if (g < 5) {
            const float nrm = sqrtf(dx * dx + dy * dy + dz * dz);
            const float inv = 1.f / fmaxf(nrm, 1e-12f);
            const float dn[3] = {dx * inv, dy * inv, dz * inv};
            if (g < 4) {
                const float sc = (float)(1 << g);
#pragma unroll
                for (int c = 0; c < 3; ++c) {
                    float tv = dn[c] * sc * INV2PI;
                    gr[18 + g * 3 + c] = f2b(sinrev(tv));
                    gr[30 + g * 3 + c] = f2b(sinrev(tv + 0.25f));
                }
            } else {
                gr[15] = f2b(dn[0]); gr[16] = f2b(dn[1]); gr[17] = f2b(dn[2]);
            }
        }
        // g>=5 bodies removed: cols 42..63 (bc1-fold 1.0 + zero pad) are constant,
        // prologue-initialized; feat writes 0..14, dir writes 15..41 -> no other writer.
    }
}

// Producer/consumer wave-specialized fused MLP: 16 waves (4/SIMD), 1 block/CU.
// R10 schedule (bar_lds barriers), no setprio (R12 A/B: null-to-negative):
//   A(i): front: enc_preload(i+1); L1(i): sE->sB; enc_compute(i+1)->sE',sG
//         back:  L3(i-1): sC->sD
//   B(i): front: L2(i): sB->sC
//         back:  bw4,5: L4(i-1): sD->sG.feat+density | bw0-3: ch1(i-2): sG->sF
//                | bw6,7: head(i-3): sF->rgb
// Buffers: sE x2 (enc j -> buf j&1), sG x4 (dir j @A(j-1) slot j&3, feat @B(j+1),
//          read @B(j+2), reuse @A(j+3)), sF x2 (ch1 j -> buf j&1, head reads @B(j+3)).
__global__ __launch_bounds__(1024, 4) void ngp_fused(
    const float* __restrict__ pos, const float* __restrict__ dir, const u16* __restrict__ ws,
    const float* __restrict__ b2, const float* __restrict__ b3,
    const float* __restrict__ b4, const float* __restrict__ bc2,
    float* __restrict__ out) {
    __shared__ __align__(16) u16 sE[2][32][HPE];    // encode out (64c), double-buffered
    __shared__ __align__(16) u16 sB[32][HPB];       // L1 out (256c)
    __shared__ __align__(16) u16 sC[32][HPB];       // L2 out (256c)
    __shared__ __align__(16) u16 sD[32][HPB];       // L3 out (256c)
    __shared__ __align__(16) u16 sG[4][32][HPE];    // color in (64c), 4-deep rotation
    __shared__ __align__(16) u16 sF[2][32][HPF];    // ch1 out (128c)
    const int t = threadIdx.x;
    const int lane = t & 63;
    const int w = t >> 6;                        // 16 waves
    const int bw = w - 8;                        // back-wave index (valid w>=8)
    const int ln = lane & 31, kh = lane >> 5;    // 32x32 frag coords
    const int lr = lane & 15, q = lane >> 4;     // 16x16 frag coords

    const u16* WT1  = ws;
    const u16* WT2  = ws + 16384;
    const u16* WT3  = ws + 81920;
    const u16* WT4  = ws + 147456;
    const u16* WTc1 = ws + 151552;
    const u16* WTc2 = ws + 159744;

    // ---- resident weights, unioned across roles (shared physical regs) ----
    short8 wrA[16], wrB[4];
    {
        const u16* pA = (w < 8) ? WT2 + (size_t)(w * 32 + ln) * 256 + kh * 8
                                : WT3 + (size_t)(bw * 32 + ln) * 256 + kh * 8;
#pragma unroll
        for (int kt = 0; kt < 16; ++kt) wrA[kt] = *(const short8*)(pA + kt * 16);
        const u16* pB = (w < 8)  ? WT1 + (size_t)(w * 32 + ln) * 64 + kh * 8
                      : (bw < 4) ? WTc1 + (size_t)(bw * 32 + ln) * 64 + kh * 8
                                 : WT1 + (size_t)ln * 64 + kh * 8;   // dummy (unused)
#pragma unroll
        for (int kt = 0; kt < 4; ++kt) wrB[kt] = *(const short8*)(pB + kt * 16);
    }

    // ---- prologue: init constant LDS columns, then encode tile 0 ----
    {
        // sG[s][r][42] = 1.0 (bc1 fold), sG[s][r][43..63] = 0, for all 4 slots.
        if (t < 128) {
            u16* gr = &sG[t >> 5][t & 31][0];
            gr[42] = 0x3F80;
#pragma unroll
            for (int c = 43; c < 64; ++c) gr[c] = 0;
        } else if (t < 192) {
            // sE[b][r][63] = 1.0 (b1 fold), both buffers.
            const int t2 = t - 128;
            sE[t2 >> 5][t2 & 31][63] = 0x3F80;
        }
        float pv[3];
        if (t < 512) {
            enc_preload(pos, dir, (long)blockIdx.x * TILES * 32, t, pv);
            enc_compute(pv, t, &sE[0][0][0], &sG[0][0][0]);
        }
        bar_lds();
    }

    for (int i = 0; i <= TILES + 2; ++i) {
        const bool dEnc = (i + 1 < TILES);
        const bool dL1  = (i < TILES);
        const bool dL3  = (i >= 1 && i <= TILES);
        const bool dC1  = (i >= 2 && i <= TILES + 1);
        const bool dHd  = (i >= 3);

        // ========== Phase A: enc_preload(i+1)+L1(i)+enc_compute(i+1) [front] | L3(i-1) [back] ==========
        float pv[3];
        if (dEnc && t < 512)
            enc_preload(pos, dir, ((long)blockIdx.x * TILES + i + 1) * 32, t, pv);
        if (dL1 && w < 8)
            layer32<4, false>(wrB, &sE[i & 1][0][0], HPE, &sB[0][0], HPB, nullptr, w * 32, ln, kh);
        if (dL3 && w >= 8)
            layer32<16, true>(wrA, &sC[0][0], HPB, &sD[0][0], HPB, b3, bw * 32, ln, kh);
        if (dEnc && t < 512)
            enc_compute(pv, t, &sE[(i + 1) & 1][0][0], &sG[(i + 1) & 3][0][0]);
        bar_lds();

        // ========== Phase B: L2(i) [front] | L4(i-1) | ch1(i-2) | head(i-3) [back] ==========
        if (dL1 && w < 8)
            layer32<16, true>(wrA, &sB[0][0], HPB, &sC[0][0], HPB, b2, w * 32, ln, kh);
        if (dL3 && w >= 8 && (bw == 4 || bw == 5)) {
            // L4(i-1): sD -> feat into sG[(i-1)&3] cols 0..14, density -> out
            const long rbM = ((long)blockIdx.x * TILES + i - 1) * 32;
            u16* sGf = &sG[(i - 1) & 3][0][0];
            const int rbase = (bw - 4) * 16;
            f32x4 acc = {0.f, 0.f, 0.f, 0.f};
#pragma unroll
            for (int kt = 0; kt < 8; ++kt) {
                const short8 aF = *(const short8*)&sD[rbase + lr][kt * 32 + q * 8];
                const short8 bF = *(const short8*)(WT4 + lr * 256 + kt * 32 + q * 8);
                acc = __builtin_amdgcn_mfma_f32_16x16x32_bf16(aF, bF, acc, 0, 0, 0);
            }
            const float bi = b4[lr];
#pragma unroll
            for (int r = 0; r < 4; ++r) {
                const float v = acc[r] + bi;
                const int gm = rbase + q * 4 + r;
                if (lr == 0)
                    out[3 * (long)NPTS + rbM + gm] = __expf(v - 1.f);
                else
                    sGf[gm * HPE + lr - 1] = f2b(v);   // feat -> cols 0..14
            }
        }
        if (dC1 && w >= 8 && bw < 4)
            layer32<4, false>(wrB, &sG[(i - 2) & 3][0][0], HPE, &sF[(i - 2) & 1][0][0], HPF,
                              nullptr, bw * 32, ln, kh);
        if (dHd && w >= 8 && (bw == 6 || bw == 7)) {
            // head(i-3): sF[(i-3)&1] -> rgb out
            const long rbH = ((long)blockIdx.x * TILES + i - 3) * 32;
            const int rbase = (bw - 6) * 16;
            f32x4 acc = {0.f, 0.f, 0.f, 0.f};
#pragma unroll
            for (int kt = 0; kt < 4; ++kt) {
                const short8 aF = *(const short8*)&sF[(i - 3) & 1][rbase + lr][kt * 32 + q * 8];
                const short8 bF = *(const short8*)(WTc2 + lr * 128 + kt * 32 + q * 8);
                acc = __builtin_amdgcn_mfma_f32_16x16x32_bf16(aF, bF, acc, 0, 0, 0);
            }
            if (lr < 3) {
                const float bi = bc2[lr];
#pragma unroll
                for (int r = 0; r < 4; ++r) {
                    const float v = acc[r] + bi;
                    const float sg = 1.f / (1.f + __expf(-v));
                    out[(rbH + rbase + q * 4 + r) * 3 + lr] = sg;
                }
            }
        }
        bar_lds();
    }
}

extern "C" void kernel_launch(void* const* d_in, const int* in_sizes, int n_in,
                              void* d_out, int out_size, void* d_ws, size_t ws_size,
                              hipStream_t stream) {
    const float* pos = (const float*)d_in[0];
    const float* dir = (const float*)d_in[1];
    const float* W1  = (const float*)d_in[2];
    const float* b1  = (const float*)d_in[3];
    const float* W2  = (const float*)d_in[4];
    const float* b2  = (const float*)d_in[5];
    const float* W3  = (const float*)d_in[6];
    const float* b3  = (const float*)d_in[7];
    const float* W4  = (const float*)d_in[8];
    const float* b4  = (const float*)d_in[9];
    const float* Wc1 = (const float*)d_in[10];
    const float* bc1 = (const float*)d_in[11];
    const float* Wc2 = (const float*)d_in[12];
    const float* bc2 = (const float*)d_in[13];
    u16* ws   = (u16*)d_ws;
    float* out = (float*)d_out;

    prep_weights<<<633, 256, 0, stream>>>(W1, b1, W2, W3, W4, Wc1, bc1, Wc2, ws);
    ngp_fused<<<NBLK, 1024, 0, stream>>>(pos, dir, ws, b2, b3, b4, bc2, out);
}

// Round 14
// 527.580 us; speedup vs baseline: 1.1075x; 1.0076x over previous
//
#include <hip/hip_runtime.h>

typedef unsigned short u16;
typedef unsigned int u32;
typedef unsigned long long u64;
typedef __attribute__((ext_vector_type(8))) short short8;
typedef __attribute__((ext_vector_type(4))) float f32x4;
typedef __attribute__((ext_vector_type(16))) float f32x16;
typedef __attribute__((ext_vector_type(2))) unsigned int u32x2;

#define NPTS 1048576
#define TILES 128
#define NBLK (NPTS / (32 * TILES))   // 256 blocks = 1 per CU
#define HPE 72    // 64-col row stride (144 B)
#define HPB 264   // 256-col row stride (528 B)
#define HPF 136   // 128-col row stride (272 B)

__device__ __forceinline__ u16 f2b(float f) {
    return (u16)((__float_as_uint(f) + 0x8000u) >> 16);
}
__device__ __forceinline__ u32 pk(float a, float b) {
    return (u32)f2b(a) | ((u32)f2b(b) << 16);
}
#define INV2PI 0.15915494309189535f
__device__ __forceinline__ float sinrev(float t) {
    t = t - floorf(t);
    return __builtin_amdgcn_sinf(t);
}

// Barrier with LDS-only drain (R10-verified +15us): __syncthreads() would drain
// vmcnt(0) (global loads + store acks) at every phase; only LDS visibility needed.
__device__ __forceinline__ void bar_lds() {
    asm volatile("s_waitcnt lgkmcnt(0)\n\ts_barrier" ::: "memory");
}

// ---------------- weight convert(fp32->bf16) + transpose/pad prepass ----------------
// ws layout (bf16), WT[n][k] row-major in k. Encoding columns are PERMUTED so enc
// threads write contiguous spans (vector ds_write) — weight rows remapped to match.
// sE cols: k<60: d=k/6, ph=(k%6)/3, c=k%3 -> W1 row (ph?33:3)+3d+c ; 60..62: raw x ;
//          63: b1 fold.
// sG cols: 0..14 feat ; 15 zero ; 16..39: j=k-16, d=j/6, ph=(j%6)/3, c=j%3 ->
//          Wc1 row (ph?30:18)+3d+c ; 40..42: dn (Wc1 rows 15..17) ; 43: bc1 fold ;
//          44..63 zero.
//  WT1  @      0 : 256 x  64
//  WT2  @  16384 : 256 x 256
//  WT3  @  81920 : 256 x 256
//  WT4  @ 147456 :  16 x 256
//  WTc1 @ 151552 : 128 x  64
//  WTc2 @ 159744 :  16 x 128   (Wc2 128x3, n>=3 -> 0)
__global__ void prep_weights(const float* __restrict__ W1, const float* __restrict__ b1,
                             const float* __restrict__ W2,
                             const float* __restrict__ W3, const float* __restrict__ W4,
                             const float* __restrict__ Wc1, const float* __restrict__ bc1,
                             const float* __restrict__ Wc2,
                             u16* __restrict__ ws) {
    int i = blockIdx.x * 256 + threadIdx.x;
    if (i < 16384) {
        int n = i >> 6, k = i & 63;
        u16 v;
        if (k < 60) {
            int d = k / 6, rem = k % 6, ph = rem / 3, c = rem % 3;
            v = f2b(W1[((ph ? 33 : 3) + 3 * d + c) * 256 + n]);
        } else if (k < 63) v = f2b(W1[(k - 60) * 256 + n]);
        else v = f2b(b1[n]);
        ws[i] = v; return;
    }
    i -= 16384;
    if (i < 65536) { int n = i >> 8, k = i & 255; ws[16384 + i]  = f2b(W2[k * 256 + n]); return; }
    i -= 65536;
    if (i < 65536) { int n = i >> 8, k = i & 255; ws[81920 + i]  = f2b(W3[k * 256 + n]); return; }
    i -= 65536;
    if (i < 4096)  { int n = i >> 8, k = i & 255; ws[147456 + i] = f2b(W4[k * 16 + n]); return; }
    i -= 4096;
    if (i < 8192) {
        int n = i >> 6, k = i & 63;
        u16 v;
        if (k < 15)       v = f2b(Wc1[k * 128 + n]);
        else if (k == 15) v = 0;
        else if (k < 40) {
            int j = k - 16, d = j / 6, rem = j % 6, ph = rem / 3, c = rem % 3;
            v = f2b(Wc1[((ph ? 30 : 18) + 3 * d + c) * 128 + n]);
        } else if (k < 43) v = f2b(Wc1[(15 + k - 40) * 128 + n]);
        else if (k == 43) v = f2b(bc1[n]);
        else v = 0;
        ws[151552 + i] = v; return;
    }
    i -= 8192;
    if (i < 2048)  { int n = i >> 7, k = i & 127; ws[159744 + i] = (n < 3) ? f2b(Wc2[k * 3 + n]) : (u16)0; return; }
}

// Epilogue for 32x32x16 (A=weights, B=acts): lane = batch row, regs = 16 neurons.
template <bool BIAS>
__device__ __forceinline__ void epi32(const f32x16& acc, u16* rowp, const float* bias,
                                      int nbase, int kh) {
#pragma unroll
    for (int g = 0; g < 4; ++g) {
        const int mq = nbase + 8 * g + 4 * kh;
        float v[4];
#pragma unroll
        for (int j = 0; j < 4; ++j) v[j] = acc[4 * g + j];
        if (BIAS) {
            const f32x4 bi = *(const f32x4*)(bias + mq);
#pragma unroll
            for (int j = 0; j < 4; ++j) v[j] += bi[j];
        }
#pragma unroll
        for (int j = 0; j < 4; ++j) v[j] = fmaxf(v[j], 0.f);
        unsigned int u[4];
#pragma unroll
        for (int j = 0; j < 4; ++j) u[j] = __float_as_uint(v[j]) + 0x8000u;
        u32x2 d;
        d.x = __builtin_amdgcn_perm(u[1], u[0], 0x07060302);
        d.y = __builtin_amdgcn_perm(u[3], u[2], 0x07060302);
        *(u32x2*)(rowp + mq) = d;
    }
}

template <int NKT, bool BIAS>
__device__ __forceinline__ void layer32(const short8* wr, const u16* src, int ss,
                                        u16* dst, int ds, const float* bias,
                                        int nbase, int ln, int kh) {
    f32x16 acc;
#pragma unroll
    for (int r = 0; r < 16; ++r) acc[r] = 0.f;
#pragma unroll
    for (int kt = 0; kt < NKT; ++kt) {
        const short8 bA = *(const short8*)(src + ln * ss + kt * 16 + kh * 8);
        acc = __builtin_amdgcn_mfma_f32_32x32x16_bf16(wr[kt], bA, acc, 0, 0, 0);
    }
    epi32<BIAS>(acc, dst + ln * ds, bias, nbase, kh);
}

// ---- encode split into preload (global loads, issued early) + compute ----
// j in [0,512): j<256 -> pos-encode job, else dir-encode job.
// Column order interleaved per-degree so each thread's outputs are CONTIGUOUS:
// pos thread g<5 writes cols 12g..12g+11 as 3x ds_write_b64 (byte 24g, 8-aligned);
// dir thread g<4 writes cols 16+6g..+5 as 3x ds_write_b32. Constant cols
// (sE 63; sG 15,43..63) prologue-initialized once.
__device__ __forceinline__ void enc_preload(const float* __restrict__ pos,
                                            const float* __restrict__ dir,
                                            long rb, int j, float* v) {
    if (j < 256) {
        const long row = rb + (j >> 3);
        v[0] = pos[row * 3 + 0]; v[1] = pos[row * 3 + 1]; v[2] = pos[row * 3 + 2];
    } else {
        const long row = rb + ((j - 256) >> 3);
        v[0] = dir[row * 3 + 0]; v[1] = dir[row * 3 + 1]; v[2] = dir[row * 3 + 2];
    }
}

__device__ __forceinline__ void enc_compute(const float* v, int j, u16* sEj, u16* sGj) {
    if (j < 256) {
        const int r = j >> 3, g = j & 7;
        float xn[3];
#pragma unroll
        for (int c = 0; c < 3; ++c) xn[c] = v[c] * (1.0f / 1.5f);
        u16* er = sEj + r * HPE;
        if (g < 5) {
            u32 wv[6];
#pragma unroll
            for (int dd = 0; dd < 2; ++dd) {
                const int d = 2 * g + dd;
                const float sc = (float)(1 << d);
                float p0[3], p1[3];
#pragma unroll
                for (int c = 0; c < 3; ++c) {
                    const float tv = xn[c] * sc * INV2PI;
                    p0[c] = sinrev(tv);
                    p1[c] = sinrev(tv + 0.25f);
                }
                wv[3 * dd + 0] = pk(p0[0], p0[1]);   // cols 6d+0, 6d+1
                wv[3 * dd + 1] = pk(p0[2], p1[0]);   // cols 6d+2, 6d+3
                wv[3 * dd + 2] = pk(p1[1], p1[2]);   // cols 6d+4, 6d+5
            }
            u64* dst = (u64*)(er + 12 * g);          // byte 24g, 8-aligned
            dst[0] = (u64)wv[0] | ((u64)wv[1] << 32);
            dst[1] = (u64)wv[2] | ((u64)wv[3] << 32);
            dst[2] = (u64)wv[4] | ((u64)wv[5] << 32);
        } else if (g == 5) {
            *(u32*)(er + 60) = pk(xn[0], xn[1]);
            er[62] = f2b(xn[2]);
            // er[63] const: prologue-initialized
        }
    } else {
        const int j2 = j - 256;
        const int r = j2 >> 3, g = j2 & 7;
        u16* gr = sGj + r * HPE;
        const float dx = v[0], dy = v[1], dz = v[2];
        if (g < 5) {
            const float nrm = sqrtf(dx * dx + dy * dy + dz * dz);
            const float inv = 1.f / fmaxf(nrm, 1e-12f);
            const float dn[3] = {dx * inv, dy * inv, dz * inv};
            if (g < 4) {
                const float sc = (float)(1 << g);
                float p0[3], p1[3];
#pragma unroll
                for (int c = 0; c < 3; ++c) {
                    const float tv = dn[c] * sc * INV2PI;
                    p0[c] = sinrev(tv);
                    p1[c] = sinrev(tv + 0.25f);
                }
                u32* dst = (u32*)(gr + 16 + 6 * g);  // byte 32+12g, 4-aligned
                dst[0] = pk(p0[0], p0[1]);           // cols 16+6g, +1
                dst[1] = pk(p0[2], p1[0]);           // +2, +3
                dst[2] = pk(p1[1], p1[2]);           // +4, +5
            } else {
                *(u32*)(gr + 40) = pk(dn[0], dn[1]); // cols 40,41
                gr[42] = f2b(dn[2]);
                // cols 15, 43..63 const: prologue-initialized
            }
        }
    }
}

// Producer/consumer wave-specialized fused MLP: 16 waves (4/SIMD), 1 block/CU.
// R13 structure (bar_lds barriers, const-cols hoisted, no setprio) + vectorized
// enc writes (interleaved column order) + ch1 NKT 4->3 (k 48..63 weights are zero):
//   A(i): front: enc_preload(i+1); L1(i): sE->sB; enc_compute(i+1)->sE',sG
//         back:  L3(i-1): sC->sD
//   B(i): front: L2(i): sB->sC
//         back:  bw4,5: L4(i-1): sD->sG.feat+density | bw0-3: ch1(i-2): sG->sF
//                | bw6,7: head(i-3): sF->rgb
// Buffers: sE x2 (enc j -> buf j&1), sG x4 (dir j @A(j-1) slot j&3, feat @B(j+1),
//          read @B(j+2), reuse @A(j+3)), sF x2 (ch1 j -> buf j&1, head reads @B(j+3)).
__global__ __launch_bounds__(1024, 4) void ngp_fused(
    const float* __restrict__ pos, const float* __restrict__ dir, const u16* __restrict__ ws,
    const float* __restrict__ b2, const float* __restrict__ b3,
    const float* __restrict__ b4, const float* __restrict__ bc2,
    float* __restrict__ out) {
    __shared__ __align__(16) u16 sE[2][32][HPE];    // encode out (64c), double-buffered
    __shared__ __align__(16) u16 sB[32][HPB];       // L1 out (256c)
    __shared__ __align__(16) u16 sC[32][HPB];       // L2 out (256c)
    __shared__ __align__(16) u16 sD[32][HPB];       // L3 out (256c)
    __shared__ __align__(16) u16 sG[4][32][HPE];    // color in (64c), 4-deep rotation
    __shared__ __align__(16) u16 sF[2][32][HPF];    // ch1 out (128c)
    const int t = threadIdx.x;
    const int lane = t & 63;
    const int w = t >> 6;                        // 16 waves
    const int bw = w - 8;                        // back-wave index (valid w>=8)
    const int ln = lane & 31, kh = lane >> 5;    // 32x32 frag coords
    const int lr = lane & 15, q = lane >> 4;     // 16x16 frag coords

    const u16* WT1  = ws;
    const u16* WT2  = ws + 16384;
    const u16* WT3  = ws + 81920;
    const u16* WT4  = ws + 147456;
    const u16* WTc1 = ws + 151552;
    const u16* WTc2 = ws + 159744;

    // ---- resident weights, unioned across roles (shared physical regs) ----
    short8 wrA[16], wrB[4];
    {
        const u16* pA = (w < 8) ? WT2 + (size_t)(w * 32 + ln) * 256 + kh * 8
                                : WT3 + (size_t)(bw * 32 + ln) * 256 + kh * 8;
#pragma unroll
        for (int kt = 0; kt < 16; ++kt) wrA[kt] = *(const short8*)(pA + kt * 16);
        const u16* pB = (w < 8)  ? WT1 + (size_t)(w * 32 + ln) * 64 + kh * 8
                      : (bw < 4) ? WTc1 + (size_t)(bw * 32 + ln) * 64 + kh * 8
                                 : WT1 + (size_t)ln * 64 + kh * 8;   // dummy (unused)
#pragma unroll
        for (int kt = 0; kt < 4; ++kt) wrB[kt] = *(const short8*)(pB + kt * 16);
    }

    // ---- prologue: init constant LDS columns, then encode tile 0 ----
    {
        // sG: col15 = 0, col43 = 1.0 (bc1 fold), cols 44..63 = 0, all 4 slots.
        if (t < 128) {
            u16* gr = &sG[t >> 5][t & 31][0];
            gr[15] = 0;
            gr[43] = 0x3F80;
#pragma unroll
            for (int c = 44; c < 64; ++c) gr[c] = 0;
        } else if (t < 192) {
            // sE[b][r][63] = 1.0 (b1 fold), both buffers.
            const int t2 = t - 128;
            sE[t2 >> 5][t2 & 31][63] = 0x3F80;
        }
        float pv[3];
        if (t < 512) {
            enc_preload(pos, dir, (long)blockIdx.x * TILES * 32, t, pv);
            enc_compute(pv, t, &sE[0][0][0], &sG[0][0][0]);
        }
        bar_lds();
    }

    for (int i = 0; i <= TILES + 2; ++i) {
        const bool dEnc = (i + 1 < TILES);
        const bool dL1  = (i < TILES);
        const bool dL3  = (i >= 1 && i <= TILES);
        const bool dC1  = (i >= 2 && i <= TILES + 1);
        const bool dHd  = (i >= 3);

        // ========== Phase A: enc_preload(i+1)+L1(i)+enc_compute(i+1) [front] | L3(i-1) [back] ==========
        float pv[3];
        if (dEnc && t < 512)
            enc_preload(pos, dir, ((long)blockIdx.x * TILES + i + 1) * 32, t, pv);
        if (dL1 && w < 8)
            layer32<4, false>(wrB, &sE[i & 1][0][0], HPE, &sB[0][0], HPB, nullptr, w * 32, ln, kh);
        if (dL3 && w >= 8)
            layer32<16, true>(wrA, &sC[0][0], HPB, &sD[0][0], HPB, b3, bw * 32, ln, kh);
        if (dEnc && t < 512)
            enc_compute(pv, t, &sE[(i + 1) & 1][0][0], &sG[(i + 1) & 3][0][0]);
        bar_lds();

        // ========== Phase B: L2(i) [front] | L4(i-1) | ch1(i-2) | head(i-3) [back] ==========
        if (dL1 && w < 8)
            layer32<16, true>(wrA, &sB[0][0], HPB, &sC[0][0], HPB, b2, w * 32, ln, kh);
        if (dL3 && w >= 8 && (bw == 4 || bw == 5)) {
            // L4(i-1): sD -> feat into sG[(i-1)&3] cols 0..14, density -> out
            const long rbM = ((long)blockIdx.x * TILES + i - 1) * 32;
            u16* sGf = &sG[(i - 1) & 3][0][0];
            const int rbase = (bw - 4) * 16;
            f32x4 acc = {0.f, 0.f, 0.f, 0.f};
#pragma unroll
            for (int kt = 0; kt < 8; ++kt) {
                const short8 aF = *(const short8*)&sD[rbase + lr][kt * 32 + q * 8];
                const short8 bF = *(const short8*)(WT4 + lr * 256 + kt * 32 + q * 8);
                acc = __builtin_amdgcn_mfma_f32_16x16x32_bf16(aF, bF, acc, 0, 0, 0);
            }
            const float bi = b4[lr];
#pragma unroll
            for (int r = 0; r < 4; ++r) {
                const float v = acc[r] + bi;
                const int gm = rbase + q * 4 + r;
                if (lr == 0)
                    out[3 * (long)NPTS + rbM + gm] = __expf(v - 1.f);
                else
                    sGf[gm * HPE + lr - 1] = f2b(v);   // feat -> cols 0..14
            }
        }
        if (dC1 && w >= 8 && bw < 4)
            layer32<3, false>(wrB, &sG[(i - 2) & 3][0][0], HPE, &sF[(i - 2) & 1][0][0], HPF,
                              nullptr, bw * 32, ln, kh);
        if (dHd && w >= 8 && (bw == 6 || bw == 7)) {
            // head(i-3): sF[(i-3)&1] -> rgb out
            const long rbH = ((long)blockIdx.x * TILES + i - 3) * 32;
            const int rbase = (bw - 6) * 16;
            f32x4 acc = {0.f, 0.f, 0.f, 0.f};
#pragma unroll
            for (int kt = 0; kt < 4; ++kt) {
                const short8 aF = *(const short8*)&sF[(i - 3) & 1][rbase + lr][kt * 32 + q * 8];
                const short8 bF = *(const short8*)(WTc2 + lr * 128 + kt * 32 + q * 8);
                acc = __builtin_amdgcn_mfma_f32_16x16x32_bf16(aF, bF, acc, 0, 0, 0);
            }
            if (lr < 3) {
                const float bi = bc2[lr];
#pragma unroll
                for (int r = 0; r < 4; ++r) {
                    const float v = acc[r] + bi;
                    const float sg = 1.f / (1.f + __expf(-v));
                    out[(rbH + rbase + q * 4 + r) * 3 + lr] = sg;
                }
            }
        }
        bar_lds();
    }
}

extern "C" void kernel_launch(void* const* d_in, const int* in_sizes, int n_in,
                              void* d_out, int out_size, void* d_ws, size_t ws_size,
                              hipStream_t stream) {
    const float* pos = (const float*)d_in[0];
    const float* dir = (const float*)d_in[1];
    const float* W1  = (const float*)d_in[2];
    const float* b1  = (const float*)d_in[3];
    const float* W2  = (const float*)d_in[4];
    const float* b2  = (const float*)d_in[5];
    const float* W3  = (const float*)d_in[6];
    const float* b3  = (const float*)d_in[7];
    const float* W4  = (const float*)d_in[8];
    const float* b4  = (const float*)d_in[9];
    const float* Wc1 = (const float*)d_in[10];
    const float* bc1 = (const float*)d_in[11];
    const float* Wc2 = (const float*)d_in[12];
    const float* bc2 = (const float*)d_in[13];
    u16* ws   = (u16*)d_ws;
    float* out = (float*)d_out;

    prep_weights<<<633, 256, 0, stream>>>(W1, b1, W2, W3, W4, Wc1, bc1, Wc2, ws);
    ngp_fused<<<NBLK, 1024, 0, stream>>>(pos, dir, ws, b2, b3, b4, bc2, out);
}